// Round 2
// baseline (539.108 us; speedup 1.0000x reference)
//
#include <hip/hip_runtime.h>

// Segment mean: out[n,:] = mean over e[i,:] where dst[i]==n; 0 if no in-edges.
// E=1.6M, D=32, N=100k.
// Pipeline: K1 bins edges into 64-node buckets (LDS hist + per-bucket global
// cursor reservation -> run-grouped record writes that merge in L2);
// K2 accumulates each bucket directly into LDS sums[64][33] via ds_add_f32
// (no per-node sort, no CSR, no per-node gather imbalance), then one
// coalesced divide+store. No big-LDS staging anywhere.

#define D_FEAT 32
#define NPB 64              // nodes per bucket
#define NB_MAX 2048         // max buckets (N <= 131072)
#define CURSOR_PAD 16       // one 64B line per cursor

// ---------------- K1: bin edges into 64-node buckets ----------------
__global__ __launch_bounds__(256) void bin_kernel(
    const int* __restrict__ dst,
    int* __restrict__ cursor,            // nb * CURSOR_PAD ints, zeroed
    unsigned int* __restrict__ buckets,  // nb * cap records: (edge<<6)|local
    int E, int nb, int cap, int chunk)
{
    __shared__ int hist[NB_MAX];
    __shared__ int gpos[NB_MAX];
    __shared__ int run [NB_MAX];
    int t = threadIdx.x;
    int cstart = blockIdx.x * chunk;
    int cn = E - cstart; if (cn > chunk) cn = chunk;
    if (cn <= 0) return;

    for (int i = t; i < nb; i += 256) hist[i] = 0;
    __syncthreads();

    // Phase A: LDS histogram over buckets (int4 loads)
    int nv = cn >> 2;
    const int4* d4 = (const int4*)(dst + cstart);   // cstart % 4 == 0 (chunk % 4 == 0)
    for (int i = t; i < nv; i += 256) {
        int4 d = d4[i];
        atomicAdd(&hist[d.x >> 6], 1);
        atomicAdd(&hist[d.y >> 6], 1);
        atomicAdd(&hist[d.z >> 6], 1);
        atomicAdd(&hist[d.w >> 6], 1);
    }
    for (int i = (nv << 2) + t; i < cn; i += 256)
        atomicAdd(&hist[dst[cstart + i] >> 6], 1);
    __syncthreads();

    // Phase B: reserve a contiguous run per nonempty bucket
    for (int i = t; i < nb; i += 256) {
        int h = hist[i];
        gpos[i] = (h > 0) ? atomicAdd(&cursor[i * CURSOR_PAD], h) : 0;
        run[i] = 0;
    }
    __syncthreads();

    // Phase C: write records; same-bucket records from this block are
    // contiguous in the bucket region -> merge in this XCD's L2.
    for (int i = t; i < nv; i += 256) {
        int4 d = d4[i];
        int g = cstart + (i << 2);
        int b0 = d.x >> 6, b1 = d.y >> 6, b2 = d.z >> 6, b3 = d.w >> 6;
        int p0 = gpos[b0] + atomicAdd(&run[b0], 1);
        int p1 = gpos[b1] + atomicAdd(&run[b1], 1);
        int p2 = gpos[b2] + atomicAdd(&run[b2], 1);
        int p3 = gpos[b3] + atomicAdd(&run[b3], 1);
        if (p0 < cap) buckets[(size_t)b0 * cap + p0] = ((unsigned)(g    ) << 6) | (unsigned)(d.x & 63);
        if (p1 < cap) buckets[(size_t)b1 * cap + p1] = ((unsigned)(g + 1) << 6) | (unsigned)(d.y & 63);
        if (p2 < cap) buckets[(size_t)b2 * cap + p2] = ((unsigned)(g + 2) << 6) | (unsigned)(d.z & 63);
        if (p3 < cap) buckets[(size_t)b3 * cap + p3] = ((unsigned)(g + 3) << 6) | (unsigned)(d.w & 63);
    }
    for (int i = (nv << 2) + t; i < cn; i += 256) {
        int g = cstart + i;
        int d = dst[g];
        int b = d >> 6;
        int p = gpos[b] + atomicAdd(&run[b], 1);
        if (p < cap) buckets[(size_t)b * cap + p] = ((unsigned)g << 6) | (unsigned)(d & 63);
    }
}

// ------- K2: per-bucket accumulate into LDS, divide, coalesced store -------
__global__ __launch_bounds__(256) void bucket_accum_kernel(
    const float4* __restrict__ e4,            // [E*8]
    const unsigned int* __restrict__ buckets,
    const int* __restrict__ cursor,
    float4* __restrict__ out4,                // [N*8]
    int N, int cap)
{
    __shared__ float sums[NPB][33];           // +1 pad: spread ds_add banks
    __shared__ int cnt[NPB];
    int t = threadIdx.x;
    int b = blockIdx.x;

    for (int i = t; i < NPB * 33; i += 256) ((float*)sums)[i] = 0.f;
    if (t < NPB) cnt[t] = 0;
    __syncthreads();

    int m = cursor[b * CURSOR_PAD]; if (m > cap) m = cap;
    const unsigned int* rec = buckets + (size_t)b * cap;

    int g = t >> 3, j = t & 7;                // 32 groups of 8 lanes
    int jb = j * 4;
    int i = g;
    for (; i + 96 < m; i += 128) {            // 4-deep MLP on the random rows
        unsigned r0 = rec[i], r1 = rec[i + 32], r2 = rec[i + 64], r3 = rec[i + 96];
        float4 v0 = e4[(size_t)(r0 >> 6) * 8 + j];
        float4 v1 = e4[(size_t)(r1 >> 6) * 8 + j];
        float4 v2 = e4[(size_t)(r2 >> 6) * 8 + j];
        float4 v3 = e4[(size_t)(r3 >> 6) * 8 + j];
        int l0 = r0 & 63, l1 = r1 & 63, l2 = r2 & 63, l3 = r3 & 63;
        atomicAdd(&sums[l0][jb + 0], v0.x); atomicAdd(&sums[l0][jb + 1], v0.y);
        atomicAdd(&sums[l0][jb + 2], v0.z); atomicAdd(&sums[l0][jb + 3], v0.w);
        atomicAdd(&sums[l1][jb + 0], v1.x); atomicAdd(&sums[l1][jb + 1], v1.y);
        atomicAdd(&sums[l1][jb + 2], v1.z); atomicAdd(&sums[l1][jb + 3], v1.w);
        atomicAdd(&sums[l2][jb + 0], v2.x); atomicAdd(&sums[l2][jb + 1], v2.y);
        atomicAdd(&sums[l2][jb + 2], v2.z); atomicAdd(&sums[l2][jb + 3], v2.w);
        atomicAdd(&sums[l3][jb + 0], v3.x); atomicAdd(&sums[l3][jb + 1], v3.y);
        atomicAdd(&sums[l3][jb + 2], v3.z); atomicAdd(&sums[l3][jb + 3], v3.w);
        if (j == 0) {
            atomicAdd(&cnt[l0], 1); atomicAdd(&cnt[l1], 1);
            atomicAdd(&cnt[l2], 1); atomicAdd(&cnt[l3], 1);
        }
    }
    for (; i < m; i += 32) {
        unsigned r0 = rec[i];
        float4 v0 = e4[(size_t)(r0 >> 6) * 8 + j];
        int l0 = r0 & 63;
        atomicAdd(&sums[l0][jb + 0], v0.x); atomicAdd(&sums[l0][jb + 1], v0.y);
        atomicAdd(&sums[l0][jb + 2], v0.z); atomicAdd(&sums[l0][jb + 3], v0.w);
        if (j == 0) atomicAdd(&cnt[l0], 1);
    }
    __syncthreads();

    // Epilogue: 64 nodes * 8 float4 = 512 slots, coalesced global stores
    for (int s = t; s < NPB * 8; s += 256) {
        int local = s >> 3, jj = (s & 7) * 4;
        int node = b * NPB + local;
        if (node < N) {
            int c = cnt[local];
            float inv = 1.0f / (float)(c > 1 ? c : 1);
            float4 r;
            r.x = sums[local][jj + 0] * inv;
            r.y = sums[local][jj + 1] * inv;
            r.z = sums[local][jj + 2] * inv;
            r.w = sums[local][jj + 3] * inv;
            out4[(size_t)node * 8 + (s & 7)] = r;
        }
    }
}

// ---------------- fallback: direct float atomics ----------------
__global__ __launch_bounds__(256) void scatter_atomic_kernel(
    const float4* __restrict__ e4, const int* __restrict__ dst,
    float* __restrict__ sums, int* __restrict__ counts, int total)
{
    int t = blockIdx.x * 256 + threadIdx.x;
    if (t >= total) return;
    int edge = t >> 3;
    int fq = t & 7;
    float4 v = e4[t];
    int d = dst[edge];
    float* o = sums + (size_t)d * D_FEAT + fq * 4;
    atomicAdd(o + 0, v.x);
    atomicAdd(o + 1, v.y);
    atomicAdd(o + 2, v.z);
    atomicAdd(o + 3, v.w);
    if (fq == 0) atomicAdd(counts + d, 1);
}

__global__ __launch_bounds__(256) void finalize_kernel(
    float4* __restrict__ out4, const int* __restrict__ counts, int total)
{
    int t = blockIdx.x * 256 + threadIdx.x;
    if (t >= total) return;
    int node = t >> 3;
    int c = counts[node];
    float inv = 1.0f / (float)(c > 1 ? c : 1);
    float4 v = out4[t];
    v.x *= inv; v.y *= inv; v.z *= inv; v.w *= inv;
    out4[t] = v;
}

extern "C" void kernel_launch(void* const* d_in, const int* in_sizes, int n_in,
                              void* d_out, int out_size, void* d_ws, size_t ws_size,
                              hipStream_t stream) {
    const float4* e4 = (const float4*)d_in[0];
    const int* dst = (const int*)d_in[1];
    int E = in_sizes[0] / D_FEAT;
    int N = out_size / D_FEAT;

    int nb = (N + NPB - 1) / NPB;
    long long avg = (E + nb - 1) / nb;
    long long thresh = avg + 8 * (long long)(__builtin_sqrt((double)avg)) + 64;
    int cap = (int)((thresh + 63) / 64 * 64);

    char* ws = (char*)d_ws;
    size_t fast_need = (size_t)nb * CURSOR_PAD * 4   // cursors (line-padded)
                     + (size_t)nb * cap * 4;          // bucket records

    if (nb <= NB_MAX && E <= (1 << 26) && ws_size >= fast_need) {
        int* cursor = (int*)ws;
        unsigned int* buckets = (unsigned int*)(ws + (size_t)nb * CURSOR_PAD * 4);

        hipMemsetAsync(cursor, 0, (size_t)nb * CURSOR_PAD * 4, stream);

        int chunk = (E + 255) / 256;
        chunk = (chunk + 3) & ~3;                    // multiple of 4 for int4 loads
        int grid1 = (E + chunk - 1) / chunk;
        bin_kernel<<<grid1, 256, 0, stream>>>(dst, cursor, buckets, E, nb, cap, chunk);
        bucket_accum_kernel<<<nb, 256, 0, stream>>>(e4, buckets, cursor,
                                                    (float4*)d_out, N, cap);
    } else {
        // fallback: direct float atomics
        int* counts = (int*)ws;
        hipMemsetAsync(d_out, 0, (size_t)out_size * sizeof(float), stream);
        hipMemsetAsync(counts, 0, (size_t)N * 4, stream);
        int total = E * (D_FEAT / 4);
        scatter_atomic_kernel<<<(total + 255) / 256, 256, 0, stream>>>(
            e4, dst, (float*)d_out, counts, total);
        int fin = N * (D_FEAT / 4);
        finalize_kernel<<<(fin + 255) / 256, 256, 0, stream>>>(
            (float4*)d_out, counts, fin);
    }
}

// Round 4
// 347.750 us; speedup vs baseline: 1.5503x; 1.5503x over previous
//
#include <hip/hip_runtime.h>

// Segment mean: out[n,:] = mean over e[i,:] where dst[i]==n; 0 if no in-edges.
// E=1.6M, D=32, N=100k.
// Pipeline:
//   K1 bin_kernel: LDS-staged bucket sort of edge records into 64-node
//      buckets (per-bucket global cursor reservation, coalesced dump).
//      chunk=3128/grid=512 -> ~51KB LDS -> 2-3 blocks/CU.
//   K2 bucket_gather_kernel (fuses old K1b+K2): per bucket, coalesced-load
//      records into LDS, 64-entry counting sort in LDS (wave scan), then
//      per-node REGISTER gather (8 lanes/node, 4-deep MLP), coalesced store.
//      No global ids2 round-trip, no LDS atomics on float data.
// (Resubmission of round-3 source: bench infra failed before measuring it.)

#define D_FEAT 32
#define NPB 64              // nodes per bucket
#define NB_MAX 2048         // max buckets (N <= 131072)
#define STAGE 3200          // max records staged per K1 block
#define CAP_LDS 2048        // max records per bucket in K2 LDS
#define CURSOR_PAD 16       // one 64B line per cursor

// ---------------- K1: staged bin into 64-node buckets ----------------
__global__ __launch_bounds__(256) void bin_kernel(
    const int* __restrict__ dst,
    int* __restrict__ cursor,            // nb * CURSOR_PAD ints, zeroed
    unsigned int* __restrict__ buckets,  // nb * cap records: (edge<<6)|local
    int E, int nb, int cap, int chunk)
{
    __shared__ int hist[NB_MAX];
    __shared__ int offs[NB_MAX];
    __shared__ int run [NB_MAX];
    __shared__ int gpos[NB_MAX];
    __shared__ unsigned int   st_rec[STAGE];
    __shared__ unsigned short st_b  [STAGE];
    __shared__ int wsum[4];

    int t = threadIdx.x;
    int cstart = blockIdx.x * chunk;
    int cn = E - cstart; if (cn > chunk) cn = chunk;
    if (cn <= 0) return;

    for (int i = t; i < nb; i += 256) hist[i] = 0;
    __syncthreads();

    // Phase A: LDS histogram over buckets (int4 loads; cstart % 4 == 0)
    int nv = cn >> 2;
    const int4* d4 = (const int4*)(dst + cstart);
    for (int i = t; i < nv; i += 256) {
        int4 d = d4[i];
        atomicAdd(&hist[d.x >> 6], 1);
        atomicAdd(&hist[d.y >> 6], 1);
        atomicAdd(&hist[d.z >> 6], 1);
        atomicAdd(&hist[d.w >> 6], 1);
    }
    for (int i = (nv << 2) + t; i < cn; i += 256)
        atomicAdd(&hist[dst[cstart + i] >> 6], 1);
    __syncthreads();

    // Phase B: exclusive scan hist -> offs/run (shfl wave scan + wave bases)
    int q = (nb + 255) >> 8;
    int lo = t * q, hi = lo + q; if (hi > nb) hi = nb;
    int sum = 0;
    for (int i = lo; i < hi; i++) sum += hist[i];
    int lane = t & 63, w = t >> 6;
    int x = sum;
    for (int off = 1; off < 64; off <<= 1) {
        int y = __shfl_up(x, off, 64);
        if (lane >= off) x += y;
    }
    if (lane == 63) wsum[w] = x;
    __syncthreads();
    int wex = 0;
    for (int u = 0; u < w; u++) wex += wsum[u];
    int ex = wex + x - sum;                   // exclusive prefix for this thread
    for (int i = lo; i < hi; i++) {
        offs[i] = ex;
        run[i]  = ex;
        ex += hist[i];
    }
    __syncthreads();

    // Phase B2: reserve contiguous global run per nonempty bucket
    for (int i = t; i < nb; i += 256) {
        int h = hist[i];
        gpos[i] = (h > 0) ? atomicAdd(&cursor[i * CURSOR_PAD], h) : 0;
    }
    __syncthreads();

    // Phase C: stage records grouped by bucket
    for (int i = t; i < nv; i += 256) {
        int4 d = d4[i];
        int g = cstart + (i << 2);
        int b0 = d.x >> 6, b1 = d.y >> 6, b2 = d.z >> 6, b3 = d.w >> 6;
        int p0 = atomicAdd(&run[b0], 1);
        int p1 = atomicAdd(&run[b1], 1);
        int p2 = atomicAdd(&run[b2], 1);
        int p3 = atomicAdd(&run[b3], 1);
        st_rec[p0] = ((unsigned)(g    ) << 6) | (unsigned)(d.x & 63); st_b[p0] = (unsigned short)b0;
        st_rec[p1] = ((unsigned)(g + 1) << 6) | (unsigned)(d.y & 63); st_b[p1] = (unsigned short)b1;
        st_rec[p2] = ((unsigned)(g + 2) << 6) | (unsigned)(d.z & 63); st_b[p2] = (unsigned short)b2;
        st_rec[p3] = ((unsigned)(g + 3) << 6) | (unsigned)(d.w & 63); st_b[p3] = (unsigned short)b3;
    }
    for (int i = (nv << 2) + t; i < cn; i += 256) {
        int g = cstart + i;
        int d = dst[g];
        int b = d >> 6;
        int p = atomicAdd(&run[b], 1);
        st_rec[p] = ((unsigned)g << 6) | (unsigned)(d & 63);
        st_b[p]   = (unsigned short)b;
    }
    __syncthreads();

    // Phase D: dump — consecutive p within a bucket -> consecutive global slots
    for (int p = t; p < cn; p += 256) {
        int b = st_b[p];
        int rel = gpos[b] + (p - offs[b]);
        if (rel < cap)
            buckets[(size_t)b * cap + rel] = st_rec[p];
    }
}

// ---- K2: per-bucket LDS counting sort + per-node register gather ----
__global__ __launch_bounds__(256) void bucket_gather_kernel(
    const float4* __restrict__ e4,            // [E*8]
    const unsigned int* __restrict__ buckets,
    const int* __restrict__ cursor,
    float4* __restrict__ out4,                // [N*8]
    int N, int cap)
{
    __shared__ unsigned int st_raw[CAP_LDS];
    __shared__ unsigned int st_ids[CAP_LDS];
    __shared__ int hist[NPB];
    __shared__ int sc  [NPB];
    __shared__ int run [NPB];

    int t = threadIdx.x;
    int b = blockIdx.x;

    if (t < NPB) hist[t] = 0;
    __syncthreads();

    int m = cursor[b * CURSOR_PAD]; if (m > cap) m = cap;
    const unsigned int* rec = buckets + (size_t)b * cap;

    // load records (coalesced) + LDS histogram over 64 locals
    for (int i = t; i < m; i += 256) {
        unsigned r = rec[i];
        st_raw[i] = r;
        atomicAdd(&hist[r & 63], 1);
    }
    __syncthreads();

    // exclusive scan of 64 counts: wave 0 only, shfl scan
    if (t < 64) {
        int v = hist[t];
        int x = v;
        for (int off = 1; off < 64; off <<= 1) {
            int y = __shfl_up(x, off, 64);
            if (t >= off) x += y;
        }
        sc[t]  = x - v;                       // exclusive
        run[t] = x - v;
    }
    __syncthreads();

    // scatter into node-sorted order (plain edge ids)
    for (int i = t; i < m; i += 256) {
        unsigned r = st_raw[i];
        int p = atomicAdd(&run[r & 63], 1);
        st_ids[p] = r >> 6;
    }
    __syncthreads();

    // per-node register gather: 8 lanes/node, 32 nodes per pass, 2 passes
    int g = t >> 3, j = t & 7;
    for (int pass = 0; pass < 2; pass++) {
        int local = pass * 32 + g;
        int node = b * NPB + local;
        int s = sc[local];
        int c = hist[local];
        float4 a0 = {0.f,0.f,0.f,0.f}, a1 = {0.f,0.f,0.f,0.f};
        float4 a2 = {0.f,0.f,0.f,0.f}, a3 = {0.f,0.f,0.f,0.f};
        int k = 0;
        for (; k + 4 <= c; k += 4) {
            unsigned e0 = st_ids[s+k],   e1 = st_ids[s+k+1];
            unsigned e2 = st_ids[s+k+2], e3 = st_ids[s+k+3];
            float4 v0 = e4[(size_t)e0*8 + j];
            float4 v1 = e4[(size_t)e1*8 + j];
            float4 v2 = e4[(size_t)e2*8 + j];
            float4 v3 = e4[(size_t)e3*8 + j];
            a0.x += v0.x; a0.y += v0.y; a0.z += v0.z; a0.w += v0.w;
            a1.x += v1.x; a1.y += v1.y; a1.z += v1.z; a1.w += v1.w;
            a2.x += v2.x; a2.y += v2.y; a2.z += v2.z; a2.w += v2.w;
            a3.x += v3.x; a3.y += v3.y; a3.z += v3.z; a3.w += v3.w;
        }
        for (; k < c; k++) {
            unsigned e0 = st_ids[s+k];
            float4 v0 = e4[(size_t)e0*8 + j];
            a0.x += v0.x; a0.y += v0.y; a0.z += v0.z; a0.w += v0.w;
        }
        if (node < N) {
            float inv = 1.0f / (float)(c > 1 ? c : 1);
            float4 r;
            r.x = (a0.x + a1.x + a2.x + a3.x) * inv;
            r.y = (a0.y + a1.y + a2.y + a3.y) * inv;
            r.z = (a0.z + a1.z + a2.z + a3.z) * inv;
            r.w = (a0.w + a1.w + a2.w + a3.w) * inv;
            out4[(size_t)node * 8 + j] = r;
        }
    }
}

// ---------------- fallback: direct float atomics ----------------
__global__ __launch_bounds__(256) void scatter_atomic_kernel(
    const float4* __restrict__ e4, const int* __restrict__ dst,
    float* __restrict__ sums, int* __restrict__ counts, int total)
{
    int t = blockIdx.x * 256 + threadIdx.x;
    if (t >= total) return;
    int edge = t >> 3;
    int fq = t & 7;
    float4 v = e4[t];
    int d = dst[edge];
    float* o = sums + (size_t)d * D_FEAT + fq * 4;
    atomicAdd(o + 0, v.x);
    atomicAdd(o + 1, v.y);
    atomicAdd(o + 2, v.z);
    atomicAdd(o + 3, v.w);
    if (fq == 0) atomicAdd(counts + d, 1);
}

__global__ __launch_bounds__(256) void finalize_kernel(
    float4* __restrict__ out4, const int* __restrict__ counts, int total)
{
    int t = blockIdx.x * 256 + threadIdx.x;
    if (t >= total) return;
    int node = t >> 3;
    int c = counts[node];
    float inv = 1.0f / (float)(c > 1 ? c : 1);
    float4 v = out4[t];
    v.x *= inv; v.y *= inv; v.z *= inv; v.w *= inv;
    out4[t] = v;
}

extern "C" void kernel_launch(void* const* d_in, const int* in_sizes, int n_in,
                              void* d_out, int out_size, void* d_ws, size_t ws_size,
                              hipStream_t stream) {
    const float4* e4 = (const float4*)d_in[0];
    const int* dst = (const int*)d_in[1];
    int E = in_sizes[0] / D_FEAT;
    int N = out_size / D_FEAT;

    int nb = (N + NPB - 1) / NPB;
    long long avg = (E + nb - 1) / nb;
    long long thresh = avg + 8 * (long long)(__builtin_sqrt((double)avg)) + 64;
    int cap = (int)((thresh + 63) / 64 * 64);

    char* ws = (char*)d_ws;
    size_t fast_need = (size_t)nb * CURSOR_PAD * 4   // cursors (line-padded)
                     + (size_t)nb * cap * 4;          // bucket records

    if (nb <= NB_MAX && cap <= CAP_LDS && E <= (1 << 25) && ws_size >= fast_need) {
        int* cursor = (int*)ws;
        unsigned int* buckets = (unsigned int*)(ws + (size_t)nb * CURSOR_PAD * 4);

        hipMemsetAsync(cursor, 0, (size_t)nb * CURSOR_PAD * 4, stream);

        // chunk: multiple of 4, <= STAGE, targeting ~512 blocks
        int chunk = (E + 511) / 512;
        chunk = (chunk + 3) & ~3;
        if (chunk > STAGE) chunk = STAGE & ~3;
        int grid1 = (E + chunk - 1) / chunk;
        bin_kernel<<<grid1, 256, 0, stream>>>(dst, cursor, buckets, E, nb, cap, chunk);
        bucket_gather_kernel<<<nb, 256, 0, stream>>>(e4, buckets, cursor,
                                                     (float4*)d_out, N, cap);
    } else {
        // fallback: direct float atomics
        int* counts = (int*)ws;
        hipMemsetAsync(d_out, 0, (size_t)out_size * sizeof(float), stream);
        hipMemsetAsync(counts, 0, (size_t)N * 4, stream);
        int total = E * (D_FEAT / 4);
        scatter_atomic_kernel<<<(total + 255) / 256, 256, 0, stream>>>(
            e4, dst, (float*)d_out, counts, total);
        int fin = N * (D_FEAT / 4);
        finalize_kernel<<<(fin + 255) / 256, 256, 0, stream>>>(
            (float4*)d_out, counts, fin);
    }
}

// Round 5
// 335.291 us; speedup vs baseline: 1.6079x; 1.0372x over previous
//
#include <hip/hip_runtime.h>

// Segment mean: out[n,:] = mean over e[i,:] where dst[i]==n; 0 if no in-edges.
// E=1.6M, D=32, N=100k.
// Pipeline:
//   K1 bin_kernel: LDS-staged bucket sort of edge records into 128-node
//      buckets (per-bucket global cursor reservation with per-block staggered
//      order, coalesced run dump). ~35KB LDS -> 4 blocks/CU.
//   K2 bucket_gather_kernel: per bucket, coalesced-load records into LDS,
//      128-entry counting sort (wave scan), then RECORD-PARALLEL gather:
//      32 groups x 8 lanes each own a contiguous slice of the node-sorted
//      records (perfect balance, no max-degree tail), 4-deep MLP on the
//      random 128B e-rows, register accumulation within same-node runs,
//      LDS float flush only at run boundaries (~3 per slice).

#define D_FEAT 32
#define NPB 128             // nodes per bucket
#define NB_MAX 1024         // max buckets (N <= 131072)
#define STAGE 3200          // max records staged per K1 block
#define CAP_LDS 2560        // max records per bucket in K2 LDS
#define CURSOR_PAD 16       // one 64B line per cursor

// ---------------- K1: staged bin into 128-node buckets ----------------
__global__ __launch_bounds__(256, 4) void bin_kernel(
    const int* __restrict__ dst,
    int* __restrict__ cursor,            // nb * CURSOR_PAD ints, zeroed
    unsigned int* __restrict__ buckets,  // nb * cap records: (edge<<7)|local
    int E, int nb, int cap, int chunk)
{
    __shared__ int hist[NB_MAX];
    __shared__ int offs[NB_MAX];
    __shared__ int run [NB_MAX];
    __shared__ int gpos[NB_MAX];
    __shared__ unsigned int   st_rec[STAGE];
    __shared__ unsigned short st_b  [STAGE];
    __shared__ int wsum[4];

    int t = threadIdx.x;
    int cstart = blockIdx.x * chunk;
    int cn = E - cstart; if (cn > chunk) cn = chunk;
    if (cn <= 0) return;

    for (int i = t; i < nb; i += 256) hist[i] = 0;
    __syncthreads();

    // Phase A: LDS histogram over buckets (int4 loads; cstart % 4 == 0)
    int nv = cn >> 2;
    const int4* d4 = (const int4*)(dst + cstart);
    for (int i = t; i < nv; i += 256) {
        int4 d = d4[i];
        atomicAdd(&hist[d.x >> 7], 1);
        atomicAdd(&hist[d.y >> 7], 1);
        atomicAdd(&hist[d.z >> 7], 1);
        atomicAdd(&hist[d.w >> 7], 1);
    }
    for (int i = (nv << 2) + t; i < cn; i += 256)
        atomicAdd(&hist[dst[cstart + i] >> 7], 1);
    __syncthreads();

    // Phase B: exclusive scan hist -> offs/run (shfl wave scan + wave bases)
    int q = (nb + 255) >> 8;
    int lo = t * q, hi = lo + q; if (hi > nb) hi = nb;
    int sum = 0;
    for (int i = lo; i < hi; i++) sum += hist[i];
    int lane = t & 63, w = t >> 6;
    int x = sum;
    for (int off = 1; off < 64; off <<= 1) {
        int y = __shfl_up(x, off, 64);
        if (lane >= off) x += y;
    }
    if (lane == 63) wsum[w] = x;
    __syncthreads();
    int wex = 0;
    for (int u = 0; u < w; u++) wex += wsum[u];
    int ex = wex + x - sum;                   // exclusive prefix for this thread
    for (int i = lo; i < hi; i++) {
        offs[i] = ex;
        run[i]  = ex;
        ex += hist[i];
    }
    __syncthreads();

    // Phase B2: reserve contiguous global run per nonempty bucket.
    // Staggered start so concurrent blocks hit different cursor lines.
    int off0 = (blockIdx.x * 199) % nb;
    for (int i = t; i < nb; i += 256) {
        int ii = i + off0; if (ii >= nb) ii -= nb;
        int h = hist[ii];
        gpos[ii] = (h > 0) ? atomicAdd(&cursor[ii * CURSOR_PAD], h) : 0;
    }
    __syncthreads();

    // Phase C: stage records grouped by bucket
    for (int i = t; i < nv; i += 256) {
        int4 d = d4[i];
        int g = cstart + (i << 2);
        int b0 = d.x >> 7, b1 = d.y >> 7, b2 = d.z >> 7, b3 = d.w >> 7;
        int p0 = atomicAdd(&run[b0], 1);
        int p1 = atomicAdd(&run[b1], 1);
        int p2 = atomicAdd(&run[b2], 1);
        int p3 = atomicAdd(&run[b3], 1);
        st_rec[p0] = ((unsigned)(g    ) << 7) | (unsigned)(d.x & 127); st_b[p0] = (unsigned short)b0;
        st_rec[p1] = ((unsigned)(g + 1) << 7) | (unsigned)(d.y & 127); st_b[p1] = (unsigned short)b1;
        st_rec[p2] = ((unsigned)(g + 2) << 7) | (unsigned)(d.z & 127); st_b[p2] = (unsigned short)b2;
        st_rec[p3] = ((unsigned)(g + 3) << 7) | (unsigned)(d.w & 127); st_b[p3] = (unsigned short)b3;
    }
    for (int i = (nv << 2) + t; i < cn; i += 256) {
        int g = cstart + i;
        int d = dst[g];
        int b = d >> 7;
        int p = atomicAdd(&run[b], 1);
        st_rec[p] = ((unsigned)g << 7) | (unsigned)(d & 127);
        st_b[p]   = (unsigned short)b;
    }
    __syncthreads();

    // Phase D: dump — consecutive p within a bucket -> consecutive global slots
    for (int p = t; p < cn; p += 256) {
        int b = st_b[p];
        int rel = gpos[b] + (p - offs[b]);
        if (rel < cap)
            buckets[(size_t)b * cap + rel] = st_rec[p];
    }
}

// ---- K2: per-bucket LDS counting sort + record-parallel balanced gather ----
__global__ __launch_bounds__(256, 4) void bucket_gather_kernel(
    const float4* __restrict__ e4,            // [E*8]
    const unsigned int* __restrict__ buckets,
    const int* __restrict__ cursor,
    float4* __restrict__ out4,                // [N*8]
    int N, int cap)
{
    __shared__ unsigned int st_raw[CAP_LDS];
    __shared__ unsigned int st_srt[CAP_LDS];  // node-sorted records
    __shared__ float sums[NPB][33];           // +1 pad
    __shared__ int hist[NPB];
    __shared__ int run [NPB];

    int t = threadIdx.x;
    int b = blockIdx.x;

    for (int i = t; i < NPB; i += 256) hist[i] = 0;
    for (int i = t; i < NPB * 33; i += 256) ((float*)sums)[i] = 0.f;
    __syncthreads();

    int m = cursor[b * CURSOR_PAD]; if (m > cap) m = cap;
    const unsigned int* rec = buckets + (size_t)b * cap;

    // load records (coalesced) + LDS histogram over 128 locals
    for (int i = t; i < m; i += 256) {
        unsigned r = rec[i];
        st_raw[i] = r;
        atomicAdd(&hist[r & 127], 1);
    }
    __syncthreads();

    // exclusive scan of 128 counts: wave 0, 2 elements per lane
    if (t < 64) {
        int v0 = hist[2 * t], v1 = hist[2 * t + 1];
        int s = v0 + v1;
        int x = s;
        for (int off = 1; off < 64; off <<= 1) {
            int y = __shfl_up(x, off, 64);
            if (t >= off) x += y;
        }
        int ex = x - s;                       // exclusive over pairs
        run[2 * t]     = ex;
        run[2 * t + 1] = ex + v0;
    }
    __syncthreads();

    // scatter into node-sorted order (keep full record: (edge<<7)|local)
    for (int i = t; i < m; i += 256) {
        unsigned r = st_raw[i];
        int p = atomicAdd(&run[r & 127], 1);
        st_srt[p] = r;
    }
    __syncthreads();

    // record-parallel gather: 32 groups x 8 lanes, contiguous slices
    int g = t >> 3, j = t & 7;
    int slice = (m + 31) >> 5;
    int s0 = g * slice;
    int s1 = s0 + slice; if (s1 > m) s1 = m;
    float* srow = &sums[0][0] + j * 4;        // lane's 4 feature columns
    float4 acc = {0.f, 0.f, 0.f, 0.f};
    int cur = -1;
    int k = s0;
    for (; k + 4 <= s1; k += 4) {
        unsigned r0 = st_srt[k], r1 = st_srt[k+1], r2 = st_srt[k+2], r3 = st_srt[k+3];
        float4 v0 = e4[(size_t)(r0 >> 7) * 8 + j];
        float4 v1 = e4[(size_t)(r1 >> 7) * 8 + j];
        float4 v2 = e4[(size_t)(r2 >> 7) * 8 + j];
        float4 v3 = e4[(size_t)(r3 >> 7) * 8 + j];
        int l0 = r0 & 127, l1 = r1 & 127, l2 = r2 & 127, l3 = r3 & 127;
        if (l0 != cur) {
            if (cur >= 0) {
                float* p = srow + cur * 33;
                atomicAdd(p + 0, acc.x); atomicAdd(p + 1, acc.y);
                atomicAdd(p + 2, acc.z); atomicAdd(p + 3, acc.w);
            }
            acc.x = acc.y = acc.z = acc.w = 0.f; cur = l0;
        }
        acc.x += v0.x; acc.y += v0.y; acc.z += v0.z; acc.w += v0.w;
        if (l1 != cur) {
            float* p = srow + cur * 33;
            atomicAdd(p + 0, acc.x); atomicAdd(p + 1, acc.y);
            atomicAdd(p + 2, acc.z); atomicAdd(p + 3, acc.w);
            acc.x = acc.y = acc.z = acc.w = 0.f; cur = l1;
        }
        acc.x += v1.x; acc.y += v1.y; acc.z += v1.z; acc.w += v1.w;
        if (l2 != cur) {
            float* p = srow + cur * 33;
            atomicAdd(p + 0, acc.x); atomicAdd(p + 1, acc.y);
            atomicAdd(p + 2, acc.z); atomicAdd(p + 3, acc.w);
            acc.x = acc.y = acc.z = acc.w = 0.f; cur = l2;
        }
        acc.x += v2.x; acc.y += v2.y; acc.z += v2.z; acc.w += v2.w;
        if (l3 != cur) {
            float* p = srow + cur * 33;
            atomicAdd(p + 0, acc.x); atomicAdd(p + 1, acc.y);
            atomicAdd(p + 2, acc.z); atomicAdd(p + 3, acc.w);
            acc.x = acc.y = acc.z = acc.w = 0.f; cur = l3;
        }
        acc.x += v3.x; acc.y += v3.y; acc.z += v3.z; acc.w += v3.w;
    }
    for (; k < s1; k++) {
        unsigned r0 = st_srt[k];
        float4 v0 = e4[(size_t)(r0 >> 7) * 8 + j];
        int l0 = r0 & 127;
        if (l0 != cur) {
            if (cur >= 0) {
                float* p = srow + cur * 33;
                atomicAdd(p + 0, acc.x); atomicAdd(p + 1, acc.y);
                atomicAdd(p + 2, acc.z); atomicAdd(p + 3, acc.w);
            }
            acc.x = acc.y = acc.z = acc.w = 0.f; cur = l0;
        }
        acc.x += v0.x; acc.y += v0.y; acc.z += v0.z; acc.w += v0.w;
    }
    if (cur >= 0) {
        float* p = srow + cur * 33;
        atomicAdd(p + 0, acc.x); atomicAdd(p + 1, acc.y);
        atomicAdd(p + 2, acc.z); atomicAdd(p + 3, acc.w);
    }
    __syncthreads();

    // Epilogue: 128 nodes * 8 float4 slots, coalesced stores
    for (int s = t; s < NPB * 8; s += 256) {
        int local = s >> 3, jj = s & 7;
        int node = b * NPB + local;
        if (node < N) {
            int c = hist[local];
            float inv = 1.0f / (float)(c > 1 ? c : 1);
            float4 r;
            r.x = sums[local][jj * 4 + 0] * inv;
            r.y = sums[local][jj * 4 + 1] * inv;
            r.z = sums[local][jj * 4 + 2] * inv;
            r.w = sums[local][jj * 4 + 3] * inv;
            out4[(size_t)node * 8 + jj] = r;
        }
    }
}

// ---------------- fallback: direct float atomics ----------------
__global__ __launch_bounds__(256) void scatter_atomic_kernel(
    const float4* __restrict__ e4, const int* __restrict__ dst,
    float* __restrict__ sums, int* __restrict__ counts, int total)
{
    int t = blockIdx.x * 256 + threadIdx.x;
    if (t >= total) return;
    int edge = t >> 3;
    int fq = t & 7;
    float4 v = e4[t];
    int d = dst[edge];
    float* o = sums + (size_t)d * D_FEAT + fq * 4;
    atomicAdd(o + 0, v.x);
    atomicAdd(o + 1, v.y);
    atomicAdd(o + 2, v.z);
    atomicAdd(o + 3, v.w);
    if (fq == 0) atomicAdd(counts + d, 1);
}

__global__ __launch_bounds__(256) void finalize_kernel(
    float4* __restrict__ out4, const int* __restrict__ counts, int total)
{
    int t = blockIdx.x * 256 + threadIdx.x;
    if (t >= total) return;
    int node = t >> 3;
    int c = counts[node];
    float inv = 1.0f / (float)(c > 1 ? c : 1);
    float4 v = out4[t];
    v.x *= inv; v.y *= inv; v.z *= inv; v.w *= inv;
    out4[t] = v;
}

extern "C" void kernel_launch(void* const* d_in, const int* in_sizes, int n_in,
                              void* d_out, int out_size, void* d_ws, size_t ws_size,
                              hipStream_t stream) {
    const float4* e4 = (const float4*)d_in[0];
    const int* dst = (const int*)d_in[1];
    int E = in_sizes[0] / D_FEAT;
    int N = out_size / D_FEAT;

    int nb = (N + NPB - 1) / NPB;
    long long avg = (E + nb - 1) / nb;
    long long thresh = avg + 8 * (long long)(__builtin_sqrt((double)avg)) + 64;
    int cap = (int)((thresh + 63) / 64 * 64);

    char* ws = (char*)d_ws;
    size_t fast_need = (size_t)nb * CURSOR_PAD * 4   // cursors (line-padded)
                     + (size_t)nb * cap * 4;          // bucket records

    if (nb <= NB_MAX && cap <= CAP_LDS && E <= (1 << 25) && ws_size >= fast_need) {
        int* cursor = (int*)ws;
        unsigned int* buckets = (unsigned int*)(ws + (size_t)nb * CURSOR_PAD * 4);

        hipMemsetAsync(cursor, 0, (size_t)nb * CURSOR_PAD * 4, stream);

        // chunk: multiple of 4, <= STAGE, targeting ~512 blocks
        int chunk = (E + 511) / 512;
        chunk = (chunk + 3) & ~3;
        if (chunk > STAGE) chunk = STAGE & ~3;
        int grid1 = (E + chunk - 1) / chunk;
        bin_kernel<<<grid1, 256, 0, stream>>>(dst, cursor, buckets, E, nb, cap, chunk);
        bucket_gather_kernel<<<nb, 256, 0, stream>>>(e4, buckets, cursor,
                                                     (float4*)d_out, N, cap);
    } else {
        // fallback: direct float atomics
        int* counts = (int*)ws;
        hipMemsetAsync(d_out, 0, (size_t)out_size * sizeof(float), stream);
        hipMemsetAsync(counts, 0, (size_t)N * 4, stream);
        int total = E * (D_FEAT / 4);
        scatter_atomic_kernel<<<(total + 255) / 256, 256, 0, stream>>>(
            e4, dst, (float*)d_out, counts, total);
        int fin = N * (D_FEAT / 4);
        finalize_kernel<<<(fin + 255) / 256, 256, 0, stream>>>(
            (float4*)d_out, counts, fin);
    }
}

// Round 7
// 332.251 us; speedup vs baseline: 1.6226x; 1.0092x over previous
//
#include <hip/hip_runtime.h>

// Segment mean: out[n,:] = mean over e[i,:] where dst[i]==n; 0 if no in-edges.
// E=1.6M, D=32, N=100k.
// Pipeline:
//   K1 bin_kernel (unchanged from r5): LDS-staged bucket sort of edge records
//      into 128-node buckets (cursor-line reservation, coalesced run dump).
//   K2 bucket_gather_kernel: 512 threads (grid=nb=782 -> ~24 waves/CU vs 12),
//      counting sort of records in LDS (records re-read from L2, no st_raw),
//      record-parallel gather with 8-deep batched prefetch (loads issued
//      back-to-back, then consumed), register accumulation within same-node
//      runs, LDS float flush at run boundaries only.
// (Resubmission of round-6 source: bench infra failed before measuring it;
//  round-3/4 showed the same failure mode was infra, not kernel.)

#define D_FEAT 32
#define NPB 128             // nodes per bucket
#define NB_MAX 1024         // max buckets (N <= 131072)
#define STAGE 3200          // max records staged per K1 block
#define CAP_LDS 2560        // max records per bucket in K2 LDS
#define CURSOR_PAD 16       // one 64B line per cursor

// ---------------- K1: staged bin into 128-node buckets ----------------
__global__ __launch_bounds__(256, 4) void bin_kernel(
    const int* __restrict__ dst,
    int* __restrict__ cursor,            // nb * CURSOR_PAD ints, zeroed
    unsigned int* __restrict__ buckets,  // nb * cap records: (edge<<7)|local
    int E, int nb, int cap, int chunk)
{
    __shared__ int hist[NB_MAX];
    __shared__ int offs[NB_MAX];
    __shared__ int run [NB_MAX];
    __shared__ int gpos[NB_MAX];
    __shared__ unsigned int   st_rec[STAGE];
    __shared__ unsigned short st_b  [STAGE];
    __shared__ int wsum[4];

    int t = threadIdx.x;
    int cstart = blockIdx.x * chunk;
    int cn = E - cstart; if (cn > chunk) cn = chunk;
    if (cn <= 0) return;

    for (int i = t; i < nb; i += 256) hist[i] = 0;
    __syncthreads();

    // Phase A: LDS histogram over buckets (int4 loads; cstart % 4 == 0)
    int nv = cn >> 2;
    const int4* d4 = (const int4*)(dst + cstart);
    for (int i = t; i < nv; i += 256) {
        int4 d = d4[i];
        atomicAdd(&hist[d.x >> 7], 1);
        atomicAdd(&hist[d.y >> 7], 1);
        atomicAdd(&hist[d.z >> 7], 1);
        atomicAdd(&hist[d.w >> 7], 1);
    }
    for (int i = (nv << 2) + t; i < cn; i += 256)
        atomicAdd(&hist[dst[cstart + i] >> 7], 1);
    __syncthreads();

    // Phase B: exclusive scan hist -> offs/run (shfl wave scan + wave bases)
    int q = (nb + 255) >> 8;
    int lo = t * q, hi = lo + q; if (hi > nb) hi = nb;
    int sum = 0;
    for (int i = lo; i < hi; i++) sum += hist[i];
    int lane = t & 63, w = t >> 6;
    int x = sum;
    for (int off = 1; off < 64; off <<= 1) {
        int y = __shfl_up(x, off, 64);
        if (lane >= off) x += y;
    }
    if (lane == 63) wsum[w] = x;
    __syncthreads();
    int wex = 0;
    for (int u = 0; u < w; u++) wex += wsum[u];
    int ex = wex + x - sum;                   // exclusive prefix for this thread
    for (int i = lo; i < hi; i++) {
        offs[i] = ex;
        run[i]  = ex;
        ex += hist[i];
    }
    __syncthreads();

    // Phase B2: reserve contiguous global run per nonempty bucket.
    // Staggered start so concurrent blocks hit different cursor lines.
    int off0 = (blockIdx.x * 199) % nb;
    for (int i = t; i < nb; i += 256) {
        int ii = i + off0; if (ii >= nb) ii -= nb;
        int h = hist[ii];
        gpos[ii] = (h > 0) ? atomicAdd(&cursor[ii * CURSOR_PAD], h) : 0;
    }
    __syncthreads();

    // Phase C: stage records grouped by bucket
    for (int i = t; i < nv; i += 256) {
        int4 d = d4[i];
        int g = cstart + (i << 2);
        int b0 = d.x >> 7, b1 = d.y >> 7, b2 = d.z >> 7, b3 = d.w >> 7;
        int p0 = atomicAdd(&run[b0], 1);
        int p1 = atomicAdd(&run[b1], 1);
        int p2 = atomicAdd(&run[b2], 1);
        int p3 = atomicAdd(&run[b3], 1);
        st_rec[p0] = ((unsigned)(g    ) << 7) | (unsigned)(d.x & 127); st_b[p0] = (unsigned short)b0;
        st_rec[p1] = ((unsigned)(g + 1) << 7) | (unsigned)(d.y & 127); st_b[p1] = (unsigned short)b1;
        st_rec[p2] = ((unsigned)(g + 2) << 7) | (unsigned)(d.z & 127); st_b[p2] = (unsigned short)b2;
        st_rec[p3] = ((unsigned)(g + 3) << 7) | (unsigned)(d.w & 127); st_b[p3] = (unsigned short)b3;
    }
    for (int i = (nv << 2) + t; i < cn; i += 256) {
        int g = cstart + i;
        int d = dst[g];
        int b = d >> 7;
        int p = atomicAdd(&run[b], 1);
        st_rec[p] = ((unsigned)g << 7) | (unsigned)(d & 127);
        st_b[p]   = (unsigned short)b;
    }
    __syncthreads();

    // Phase D: dump — consecutive p within a bucket -> consecutive global slots
    for (int p = t; p < cn; p += 256) {
        int b = st_b[p];
        int rel = gpos[b] + (p - offs[b]);
        if (rel < cap)
            buckets[(size_t)b * cap + rel] = st_rec[p];
    }
}

// ---- K2: per-bucket LDS counting sort + record-parallel balanced gather ----
#define CONSUME(r, v)                                                          \
    {                                                                          \
        int l = (int)((r) & 127);                                              \
        if (l != cur) {                                                        \
            if (cur >= 0) {                                                    \
                float* p = srow + cur * 33;                                    \
                atomicAdd(p + 0, acc.x); atomicAdd(p + 1, acc.y);              \
                atomicAdd(p + 2, acc.z); atomicAdd(p + 3, acc.w);              \
            }                                                                  \
            acc.x = acc.y = acc.z = acc.w = 0.f; cur = l;                      \
        }                                                                      \
        acc.x += (v).x; acc.y += (v).y; acc.z += (v).z; acc.w += (v).w;        \
    }

__global__ __launch_bounds__(512, 6) void bucket_gather_kernel(
    const float4* __restrict__ e4,            // [E*8]
    const unsigned int* __restrict__ buckets,
    const int* __restrict__ cursor,
    float4* __restrict__ out4,                // [N*8]
    int N, int cap)
{
    __shared__ unsigned int st_srt[CAP_LDS];  // node-sorted records
    __shared__ float sums[NPB][33];           // +1 pad
    __shared__ int hist[NPB];
    __shared__ int run [NPB];

    int t = threadIdx.x;
    int b = blockIdx.x;

    for (int i = t; i < NPB; i += 512) hist[i] = 0;
    for (int i = t; i < NPB * 33; i += 512) ((float*)sums)[i] = 0.f;
    __syncthreads();

    int m = cursor[b * CURSOR_PAD]; if (m > cap) m = cap;
    const unsigned int* rec = buckets + (size_t)b * cap;

    // pass 1: LDS histogram over 128 locals (coalesced global read)
    for (int i = t; i < m; i += 512)
        atomicAdd(&hist[rec[i] & 127], 1);
    __syncthreads();

    // exclusive scan of 128 counts: wave 0, 2 elements per lane
    if (t < 64) {
        int v0 = hist[2 * t], v1 = hist[2 * t + 1];
        int s = v0 + v1;
        int x = s;
        for (int off = 1; off < 64; off <<= 1) {
            int y = __shfl_up(x, off, 64);
            if (t >= off) x += y;
        }
        int ex = x - s;                       // exclusive over pairs
        run[2 * t]     = ex;
        run[2 * t + 1] = ex + v0;
    }
    __syncthreads();

    // pass 2: scatter into node-sorted order (records re-read; L2-hot)
    for (int i = t; i < m; i += 512) {
        unsigned r = rec[i];
        int p = atomicAdd(&run[r & 127], 1);
        st_srt[p] = r;
    }
    __syncthreads();

    // record-parallel gather: 64 groups x 8 lanes, contiguous slices,
    // 8-deep batched prefetch then consume.
    int g = t >> 3, j = t & 7;
    int slice = (m + 63) >> 6;
    int s0 = g * slice;
    int s1 = s0 + slice; if (s1 > m) s1 = m;
    float* srow = &sums[0][0] + j * 4;        // lane's 4 feature columns
    float4 acc = {0.f, 0.f, 0.f, 0.f};
    int cur = -1;
    int k = s0;
    for (; k + 8 <= s1; k += 8) {
        unsigned r0 = st_srt[k],   r1 = st_srt[k+1], r2 = st_srt[k+2], r3 = st_srt[k+3];
        unsigned r4 = st_srt[k+4], r5 = st_srt[k+5], r6 = st_srt[k+6], r7 = st_srt[k+7];
        float4 v0 = e4[(size_t)(r0 >> 7) * 8 + j];
        float4 v1 = e4[(size_t)(r1 >> 7) * 8 + j];
        float4 v2 = e4[(size_t)(r2 >> 7) * 8 + j];
        float4 v3 = e4[(size_t)(r3 >> 7) * 8 + j];
        float4 v4 = e4[(size_t)(r4 >> 7) * 8 + j];
        float4 v5 = e4[(size_t)(r5 >> 7) * 8 + j];
        float4 v6 = e4[(size_t)(r6 >> 7) * 8 + j];
        float4 v7 = e4[(size_t)(r7 >> 7) * 8 + j];
        CONSUME(r0, v0); CONSUME(r1, v1); CONSUME(r2, v2); CONSUME(r3, v3);
        CONSUME(r4, v4); CONSUME(r5, v5); CONSUME(r6, v6); CONSUME(r7, v7);
    }
    for (; k < s1; k++) {
        unsigned r0 = st_srt[k];
        float4 v0 = e4[(size_t)(r0 >> 7) * 8 + j];
        CONSUME(r0, v0);
    }
    if (cur >= 0) {
        float* p = srow + cur * 33;
        atomicAdd(p + 0, acc.x); atomicAdd(p + 1, acc.y);
        atomicAdd(p + 2, acc.z); atomicAdd(p + 3, acc.w);
    }
    __syncthreads();

    // Epilogue: 128 nodes * 8 float4 slots, coalesced stores
    for (int s = t; s < NPB * 8; s += 512) {
        int local = s >> 3, jj = s & 7;
        int node = b * NPB + local;
        if (node < N) {
            int c = hist[local];
            float inv = 1.0f / (float)(c > 1 ? c : 1);
            float4 r;
            r.x = sums[local][jj * 4 + 0] * inv;
            r.y = sums[local][jj * 4 + 1] * inv;
            r.z = sums[local][jj * 4 + 2] * inv;
            r.w = sums[local][jj * 4 + 3] * inv;
            out4[(size_t)node * 8 + jj] = r;
        }
    }
}

// ---------------- fallback: direct float atomics ----------------
__global__ __launch_bounds__(256) void scatter_atomic_kernel(
    const float4* __restrict__ e4, const int* __restrict__ dst,
    float* __restrict__ sums, int* __restrict__ counts, int total)
{
    int t = blockIdx.x * 256 + threadIdx.x;
    if (t >= total) return;
    int edge = t >> 3;
    int fq = t & 7;
    float4 v = e4[t];
    int d = dst[edge];
    float* o = sums + (size_t)d * D_FEAT + fq * 4;
    atomicAdd(o + 0, v.x);
    atomicAdd(o + 1, v.y);
    atomicAdd(o + 2, v.z);
    atomicAdd(o + 3, v.w);
    if (fq == 0) atomicAdd(counts + d, 1);
}

__global__ __launch_bounds__(256) void finalize_kernel(
    float4* __restrict__ out4, const int* __restrict__ counts, int total)
{
    int t = blockIdx.x * 256 + threadIdx.x;
    if (t >= total) return;
    int node = t >> 3;
    int c = counts[node];
    float inv = 1.0f / (float)(c > 1 ? c : 1);
    float4 v = out4[t];
    v.x *= inv; v.y *= inv; v.z *= inv; v.w *= inv;
    out4[t] = v;
}

extern "C" void kernel_launch(void* const* d_in, const int* in_sizes, int n_in,
                              void* d_out, int out_size, void* d_ws, size_t ws_size,
                              hipStream_t stream) {
    const float4* e4 = (const float4*)d_in[0];
    const int* dst = (const int*)d_in[1];
    int E = in_sizes[0] / D_FEAT;
    int N = out_size / D_FEAT;

    int nb = (N + NPB - 1) / NPB;
    long long avg = (E + nb - 1) / nb;
    long long thresh = avg + 8 * (long long)(__builtin_sqrt((double)avg)) + 64;
    int cap = (int)((thresh + 63) / 64 * 64);

    char* ws = (char*)d_ws;
    size_t fast_need = (size_t)nb * CURSOR_PAD * 4   // cursors (line-padded)
                     + (size_t)nb * cap * 4;          // bucket records

    if (nb <= NB_MAX && cap <= CAP_LDS && E <= (1 << 24) && ws_size >= fast_need) {
        int* cursor = (int*)ws;
        unsigned int* buckets = (unsigned int*)(ws + (size_t)nb * CURSOR_PAD * 4);

        hipMemsetAsync(cursor, 0, (size_t)nb * CURSOR_PAD * 4, stream);

        // chunk: multiple of 4, <= STAGE, targeting ~512 blocks
        int chunk = (E + 511) / 512;
        chunk = (chunk + 3) & ~3;
        if (chunk > STAGE) chunk = STAGE & ~3;
        int grid1 = (E + chunk - 1) / chunk;
        bin_kernel<<<grid1, 256, 0, stream>>>(dst, cursor, buckets, E, nb, cap, chunk);
        bucket_gather_kernel<<<nb, 512, 0, stream>>>(e4, buckets, cursor,
                                                     (float4*)d_out, N, cap);
    } else {
        // fallback: direct float atomics
        int* counts = (int*)ws;
        hipMemsetAsync(d_out, 0, (size_t)out_size * sizeof(float), stream);
        hipMemsetAsync(counts, 0, (size_t)N * 4, stream);
        int total = E * (D_FEAT / 4);
        scatter_atomic_kernel<<<(total + 255) / 256, 256, 0, stream>>>(
            e4, dst, (float*)d_out, counts, total);
        int fin = N * (D_FEAT / 4);
        finalize_kernel<<<(fin + 255) / 256, 256, 0, stream>>>(
            (float4*)d_out, counts, fin);
    }
}